// Round 10
// baseline (329.948 us; speedup 1.0000x reference)
//
#include <hip/hip_runtime.h>
#include <hip/hip_fp16.h>

#define B_     4096
#define INE_   4096
#define INBR_  8192
#define D_     2048
#define KE_    50
#define KPAD_  52
#define CAP_   512

// ---------- helpers ----------
__device__ __forceinline__ unsigned packh2(float a, float b) {
  __half2 h = __floats2half2_rn(a, b);
  return __builtin_bit_cast(unsigned, h);
}
__device__ __forceinline__ float2 unpackh2(unsigned u) {
  __half2 h = __builtin_bit_cast(__half2, u);
  return __half22float2(h);
}

// ---------- top-k body (proven) ----------
// 8-row LDS layout byte offset: c -> ((c>>2)<<4) | ((c&3)<<14), max 65520 (fits u16).
// Excitation: packed records muT[13][2048] = uint4 {u16 off[4], f16 val[4]}.
// Inhibition: flat u32 offset + f32 value.
__device__ void topk_body(const float* __restrict__ W, int row, int k, int kpad,
                          float hi, float t0, float vscale,
                          uint4* __restrict__ muT,
                          unsigned* __restrict__ out_off, float* __restrict__ out_val)
{
  const int t = threadIdx.x;
  const float* wr = W + (size_t)row * INE_;

  __shared__ float cval[CAP_];
  __shared__ int   ccol[CAP_];
  __shared__ int   scnt;
  __shared__ int   red[4];

  float thr = t0;
  int M = 0;
  for (int attempt = 0; attempt < 8; ++attempt) {
    int local = 0;
    #pragma unroll
    for (int j = 0; j < 4; ++j) {
      float4 w4 = *reinterpret_cast<const float4*>(wr + 4 * (t + 256 * j));
      local += (w4.x > thr) + (w4.y > thr) + (w4.z > thr) + (w4.w > thr);
    }
    #pragma unroll
    for (int off = 32; off > 0; off >>= 1) local += __shfl_down(local, off);
    if ((t & 63) == 0) red[t >> 6] = local;
    __syncthreads();
    M = red[0] + red[1] + red[2] + red[3];
    __syncthreads();
    if (M >= k && M <= CAP_) break;
    if (M < k) thr = hi - (hi - thr) * 4.0f;
    else       thr = hi - (hi - thr) * 0.5f;
  }

  if (t == 0) scnt = 0;
  __syncthreads();
  #pragma unroll
  for (int j = 0; j < 4; ++j) {
    int cbase = 4 * (t + 256 * j);
    float4 w4 = *reinterpret_cast<const float4*>(wr + cbase);
    float wv[4] = {w4.x, w4.y, w4.z, w4.w};
    #pragma unroll
    for (int q = 0; q < 4; ++q) {
      if (wv[q] > thr) {
        int pp = atomicAdd(&scnt, 1);
        if (pp < CAP_) { cval[pp] = wv[q]; ccol[pp] = cbase + q; }
      }
    }
  }
  __syncthreads();
  M = scnt < CAP_ ? scnt : CAP_;

  for (int i = t; i < M; i += 256) {
    float wi = cval[i]; int ci = ccol[i];
    int rank = 0;
    for (int m = 0; m < M; ++m) {
      float wm = cval[m]; int cm = ccol[m];
      rank += (wm > wi || (wm == wi && cm < ci)) ? 1 : 0;
    }
    if (rank < k) {
      unsigned c = (unsigned)ci;
      unsigned off = ((c >> 2) << 4) | ((c & 3u) << 14);
      if (kpad == 1) {
        out_off[row] = off;
        out_val[row] = wi * vscale;
      } else {
        char* rec = (char*)muT + ((size_t)(rank >> 2) * D_ + row) * 16;
        reinterpret_cast<unsigned short*>(rec)[rank & 3] = (unsigned short)off;
        reinterpret_cast<__half*>(rec)[4 + (rank & 3)] =
            __float2half_rn(wi * vscale);
      }
    }
  }
  if (kpad > 1 && t < kpad - k) {
    int slot = k + t;
    char* rec = (char*)muT + ((size_t)(slot >> 2) * D_ + row) * 16;
    reinterpret_cast<unsigned short*>(rec)[slot & 3] = 0;
    reinterpret_cast<__half*>(rec)[4 + (slot & 3)] = __float2half_rn(0.0f);
  }
}

// ---------- K1: combined prep ----------
__global__ __launch_bounds__(256) void prep_kernel(
    const float* __restrict__ wexc, const float* __restrict__ winh,
    const float* __restrict__ wblk,
    uint4* __restrict__ muT,
    unsigned* __restrict__ so_inh, float* __restrict__ vi_inh,
    float* __restrict__ wdiag)
{
  const int bid = blockIdx.x;
  const float hi = 0.015625f;
  if (bid < 2048) {
    topk_body(wexc, bid, KE_, KPAD_, hi, hi * (1.0f - 200.0f / 4096.0f), 1.0f,
              muT, nullptr, nullptr);
  } else if (bid < 4096) {
    topk_body(winh, bid - 2048, 1, 1, hi, hi * (1.0f - 48.0f / 4096.0f), -50.0f,
              nullptr, so_inh, vi_inh);
  } else {
    const int t = threadIdx.x;
    #pragma unroll
    for (int j = 0; j < 8; ++j) {
      int d = t + 256 * j;
      float4 w = *reinterpret_cast<const float4*>(wblk + (size_t)d * (INBR_ + 4));
      reinterpret_cast<float4*>(wdiag)[d] = w;
    }
  }
}

// ---------- fused E+I+BR kernel, templated for ablation ----------
// MODE bit0: skip LDS gathers (reuse metadata word as data)
// MODE bit1: skip metadata loads (LCG-hashed offsets, const values)
__device__ __forceinline__ void stage_rows8(const float* __restrict__ src,
                                            unsigned* xs, int b0, int p, int Q) {
  const float* r0p = src + (size_t)(b0 + 2 * p)     * INE_;
  const float* r1p = src + (size_t)(b0 + 2 * p + 1) * INE_;
  #pragma unroll
  for (int m = 0; m < 8; ++m) {
    int c0 = 4 * Q + 512 * m;
    float4 fa = *reinterpret_cast<const float4*>(r0p + c0);
    float4 fb = *reinterpret_cast<const float4*>(r1p + c0);
    int wb = 4 * (Q + 128 * m) + p;
    xs[wb]          = packh2(fa.x, fb.x);
    xs[wb + 4096]   = packh2(fa.y, fb.y);
    xs[wb + 8192]   = packh2(fa.z, fb.z);
    xs[wb + 12288]  = packh2(fa.w, fb.w);
  }
}

__device__ __forceinline__ uint4 ld16(const char* ldsb, unsigned off) {
  return *reinterpret_cast<const uint4*>(ldsb + off);
}

#define FMA8(R, G, WV) do {                                                \
    float2 f0 = unpackh2((G).x), f1 = unpackh2((G).y);                     \
    float2 f2 = unpackh2((G).z), f3 = unpackh2((G).w);                     \
    acc[R][0] = fmaf(f0.x, (WV), acc[R][0]);                               \
    acc[R][1] = fmaf(f0.y, (WV), acc[R][1]);                               \
    acc[R][2] = fmaf(f1.x, (WV), acc[R][2]);                               \
    acc[R][3] = fmaf(f1.y, (WV), acc[R][3]);                               \
    acc[R][4] = fmaf(f2.x, (WV), acc[R][4]);                               \
    acc[R][5] = fmaf(f2.y, (WV), acc[R][5]);                               \
    acc[R][6] = fmaf(f3.x, (WV), acc[R][6]);                               \
    acc[R][7] = fmaf(f3.y, (WV), acc[R][7]);                               \
  } while (0)

template <int MODE>
__global__ __launch_bounds__(512, 4) void fused_ei_t(
    const float* __restrict__ xe, const float* __restrict__ xi,
    const float* __restrict__ xbr, const float* __restrict__ wdiag,
    const uint4* __restrict__ muT,
    const unsigned* __restrict__ so_inh, const float* __restrict__ vi_inh,
    float* __restrict__ act)
{
  __shared__ unsigned xs[16384];          // 64 KiB -> 2 blocks/CU
  const int t  = threadIdx.x;
  const int b0 = blockIdx.x * 8;
  const int p  = t & 3;
  const int Q  = t >> 2;

  float acc[4][8];
  #pragma unroll
  for (int r = 0; r < 4; ++r)
    #pragma unroll
    for (int b = 0; b < 8; ++b) acc[r][b] = 0.0f;

  const char* ldsb = reinterpret_cast<const char*>(xs);

  stage_rows8(xe, xs, b0, p, Q);

  // prefetch first half of xi into regs
  float4 xia[4], xib[4];
  {
    const float* xr0 = xi + (size_t)(b0 + 2 * p)     * INE_;
    const float* xr1 = xi + (size_t)(b0 + 2 * p + 1) * INE_;
    #pragma unroll
    for (int m = 0; m < 4; ++m) {
      xia[m] = *reinterpret_cast<const float4*>(xr0 + 4 * Q + 512 * m);
      xib[m] = *reinterpret_cast<const float4*>(xr1 + 4 * Q + 512 * m);
    }
  }
  unsigned oi[4]; float viv[4];
  #pragma unroll
  for (int r = 0; r < 4; ++r) {
    oi[r]  = so_inh[t + 512 * r];
    viv[r] = vi_inh[t + 512 * r];
  }
  __syncthreads();

  // ---- phase E ----
  for (int ii = 0; ii < KPAD_ / 4; ++ii) {
    uint4 m[4];
    if constexpr ((MODE & 2) == 0) {
      #pragma unroll
      for (int r = 0; r < 4; ++r) m[r] = muT[ii * D_ + t + 512 * r];
    } else {
      // hashed metadata with same offset randomness; no global load
      unsigned base = (unsigned)t * 2654435761u + (unsigned)ii * 0x9E3779B9u;
      #pragma unroll
      for (int r = 0; r < 4; ++r) {
        unsigned h0 = base + r * 0x1B873593u;
        unsigned o0 = ((h0       ) & 4095u) << 4;
        unsigned o1 = ((h0 >> 8  ) & 4095u) << 4;
        unsigned o2 = ((h0 >> 16 ) & 4095u) << 4;
        unsigned o3 = (((h0 >> 24) ^ h0) & 4095u) << 4;
        m[r].x = o0 | (o1 << 16);
        m[r].y = o2 | (o3 << 16);
        m[r].z = 0x3C003C00u;   // f16 1.0, 1.0
        m[r].w = 0x3C003C00u;
      }
    }
    #pragma unroll
    for (int half = 0; half < 2; ++half) {
      uint4 g[2][4];
      #pragma unroll
      for (int rr = 0; rr < 2; ++rr) {
        const int r = 2 * half + rr;
        if constexpr ((MODE & 1) == 0) {
          g[rr][0] = ld16(ldsb, m[r].x & 0xFFFFu);
          g[rr][1] = ld16(ldsb, m[r].x >> 16);
          g[rr][2] = ld16(ldsb, m[r].y & 0xFFFFu);
          g[rr][3] = ld16(ldsb, m[r].y >> 16);
        } else {
          // reuse metadata word as data: no LDS read, deps preserved
          g[rr][0] = m[r];
          g[rr][1] = uint4{m[r].y, m[r].x, m[r].w, m[r].z};
          g[rr][2] = uint4{m[r].z, m[r].w, m[r].x, m[r].y};
          g[rr][3] = uint4{m[r].w, m[r].z, m[r].y, m[r].x};
        }
      }
      #pragma unroll
      for (int rr = 0; rr < 2; ++rr) {
        const int r = 2 * half + rr;
        float2 vA = unpackh2(m[r].z);
        float2 vB = unpackh2(m[r].w);
        FMA8(r, g[rr][0], vA.x);
        FMA8(r, g[rr][1], vA.y);
        FMA8(r, g[rr][2], vB.x);
        FMA8(r, g[rr][3], vB.y);
      }
    }
  }
  __syncthreads();

  if constexpr ((MODE & 1) != 0) {
    // keep xe staging alive without gathers (anti-DCE, rule #17)
    unsigned tmp = xs[t];
    asm volatile("" :: "v"(tmp));
  }

  // ---- stage xi (half from regs, half from HBM) ----
  #pragma unroll
  for (int m = 0; m < 4; ++m) {
    int wb = 4 * (Q + 128 * m) + p;
    xs[wb]          = packh2(xia[m].x, xib[m].x);
    xs[wb + 4096]   = packh2(xia[m].y, xib[m].y);
    xs[wb + 8192]   = packh2(xia[m].z, xib[m].z);
    xs[wb + 12288]  = packh2(xia[m].w, xib[m].w);
  }
  {
    const float* xr0 = xi + (size_t)(b0 + 2 * p)     * INE_;
    const float* xr1 = xi + (size_t)(b0 + 2 * p + 1) * INE_;
    #pragma unroll
    for (int m = 4; m < 8; ++m) {
      int c0 = 4 * Q + 512 * m;
      float4 fa = *reinterpret_cast<const float4*>(xr0 + c0);
      float4 fb = *reinterpret_cast<const float4*>(xr1 + c0);
      int wb = 4 * (Q + 128 * m) + p;
      xs[wb]          = packh2(fa.x, fb.x);
      xs[wb + 4096]   = packh2(fa.y, fb.y);
      xs[wb + 8192]   = packh2(fa.z, fb.z);
      xs[wb + 12288]  = packh2(fa.w, fb.w);
    }
  }
  __syncthreads();

  // ---- phase I ----
  {
    uint4 gi[4];
    #pragma unroll
    for (int r = 0; r < 4; ++r) gi[r] = ld16(ldsb, oi[r]);
    #pragma unroll
    for (int r = 0; r < 4; ++r) FMA8(r, gi[r], viv[r]);
  }

  // ---- phase BR ----
  #pragma unroll
  for (int r = 0; r < 4; ++r) {
    const int d = t + 512 * r;
    float4 wb4 = reinterpret_cast<const float4*>(wdiag)[d];
    #pragma unroll
    for (int b = 0; b < 8; ++b) {
      float4 xb4 = *reinterpret_cast<const float4*>(
          xbr + (size_t)(b0 + b) * INBR_ + 4 * d);
      acc[r][b] += xb4.x * wb4.x + xb4.y * wb4.y + xb4.z * wb4.z + xb4.w * wb4.w;
    }
  }

  // ---- write act (probes also write; final MODE0 launch overwrites all) ----
  #pragma unroll
  for (int r = 0; r < 4; ++r) {
    const int d = t + 512 * r;
    #pragma unroll
    for (int b = 0; b < 8; ++b)
      act[(size_t)(b0 + b) * D_ + d] = acc[r][b];
  }
}

// ---------- K3a: column sums/sumsq ----------
__global__ __launch_bounds__(256) void reduce_stats(
    const float* __restrict__ act, float* __restrict__ sums,
    float* __restrict__ sumsq)
{
  const int dg = blockIdx.x & 63;
  const int rg = blockIdx.x >> 6;
  const int tx = threadIdx.x & 31;
  const int ty = threadIdx.x >> 5;
  const int d  = dg * 32 + tx;

  float s = 0.0f, s2 = 0.0f;
  #pragma unroll 4
  for (int i = 0; i < 64; ++i) {
    int row = rg * 512 + ty + 8 * i;
    float a = act[(size_t)row * D_ + d];
    s += a;
    s2 = fmaf(a, a, s2);
  }
  __shared__ float ls[2][8][32];
  ls[0][ty][tx] = s;
  ls[1][ty][tx] = s2;
  __syncthreads();
  if (ty == 0) {
    #pragma unroll
    for (int j = 1; j < 8; ++j) { s += ls[0][j][tx]; s2 += ls[1][j][tx]; }
    atomicAdd(&sums[d], s);
    atomicAdd(&sumsq[d], s2);
  }
}

// ---------- K3b: finalize + normalize + sigmoid ----------
__global__ __launch_bounds__(256) void tail_kernel(
    const float* __restrict__ act, float* __restrict__ out,
    const float* __restrict__ sums, const float* __restrict__ sumsq,
    const float* __restrict__ gamma, const float* __restrict__ beta)
{
  __shared__ float scsh[2 * D_];
  const int tid = threadIdx.x;
  #pragma unroll
  for (int j = 0; j < 8; ++j) {
    int d = tid + 256 * j;
    float mean = sums[d]  * (1.0f / B_);
    float var  = sumsq[d] * (1.0f / B_) - mean * mean;
    float rstd = rsqrtf(var + 1e-5f);
    float sc   = gamma[d] * rstd;
    scsh[2 * d]     = sc;
    scsh[2 * d + 1] = fmaf(-mean, sc, beta[d]);
  }
  __syncthreads();

  const int r0 = blockIdx.x * 8;
  for (int rr = 0; rr < 8; ++rr) {
    const float4* ap = reinterpret_cast<const float4*>(act + (size_t)(r0 + rr) * D_);
    float4*       op = reinterpret_cast<float4*>(out + (size_t)(r0 + rr) * D_);
    #pragma unroll
    for (int i2 = 0; i2 < 2; ++i2) {
      int i = tid + 256 * i2;
      float4 a = ap[i];
      const float4* sp = reinterpret_cast<const float4*>(scsh + 8 * i);
      float4 s0 = sp[0];
      float4 s1 = sp[1];
      float z0 = fmaf(a.x, s0.x, s0.y);
      float z1 = fmaf(a.y, s0.z, s0.w);
      float z2 = fmaf(a.z, s1.x, s1.y);
      float z3 = fmaf(a.w, s1.z, s1.w);
      float4 o;
      o.x = 1.0f / (1.0f + __expf(-z0));
      o.y = 1.0f / (1.0f + __expf(-z1));
      o.z = 1.0f / (1.0f + __expf(-z2));
      o.w = 1.0f / (1.0f + __expf(-z3));
      op[i] = o;
    }
  }
}

extern "C" void kernel_launch(void* const* d_in, const int* in_sizes, int n_in,
                              void* d_out, int out_size, void* d_ws, size_t ws_size,
                              hipStream_t stream) {
  const float* xe    = (const float*)d_in[0];
  const float* xi    = (const float*)d_in[1];
  const float* xbr   = (const float*)d_in[2];
  const float* wexc  = (const float*)d_in[3];
  const float* winh  = (const float*)d_in[4];
  const float* wblk  = (const float*)d_in[5];
  const float* gamma = (const float*)d_in[6];
  const float* beta  = (const float*)d_in[7];
  float* out = (float*)d_out;

  char* ws = (char*)d_ws;
  uint4*    muT    = (uint4*)   (ws + 0);         // [13][2048] uint4
  unsigned* so_inh = (unsigned*)(ws + 425984);
  float*    vi_inh = (float*)   (ws + 434176);
  float*    wdiag  = (float*)   (ws + 442368);
  float*    sums   = (float*)   (ws + 475136);
  float*    sumsq  = (float*)   (ws + 483328);
  float*    act    = (float*)   (ws + 1048576);   // 32 MiB

  hipMemsetAsync(sums, 0, 2 * D_ * sizeof(float), stream);

  prep_kernel<<<dim3(4097), dim3(256), 0, stream>>>(
      wexc, winh, wblk, muT, so_inh, vi_inh, wdiag);

  // ---- ablation probes (results discarded; act fully overwritten below) ----
  fused_ei_t<3><<<dim3(B_ / 8), dim3(512), 0, stream>>>(   // base: stage+VALU+I+BR
      xe, xi, xbr, wdiag, muT, so_inh, vi_inh, act);
  fused_ei_t<1><<<dim3(B_ / 8), dim3(512), 0, stream>>>(   // +meta, no gathers
      xe, xi, xbr, wdiag, muT, so_inh, vi_inh, act);
  fused_ei_t<2><<<dim3(B_ / 8), dim3(512), 0, stream>>>(   // +gathers, no meta
      xe, xi, xbr, wdiag, muT, so_inh, vi_inh, act);

  // ---- real computation ----
  fused_ei_t<0><<<dim3(B_ / 8), dim3(512), 0, stream>>>(
      xe, xi, xbr, wdiag, muT, so_inh, vi_inh, act);

  reduce_stats<<<dim3(512), dim3(256), 0, stream>>>(act, sums, sumsq);
  tail_kernel<<<dim3(512), dim3(256), 0, stream>>>(
      act, out, sums, sumsq, gamma, beta);
}

// Round 11
// 144.775 us; speedup vs baseline: 2.2790x; 2.2790x over previous
//
#include <hip/hip_runtime.h>
#include <hip/hip_fp16.h>

#define B_     4096
#define INE_   4096
#define INBR_  8192
#define D_     2048
#define KE_    50
#define KPAD_  52
#define CAP_   512

// ---------- helpers ----------
__device__ __forceinline__ unsigned packh2(float a, float b) {
  __half2 h = __floats2half2_rn(a, b);
  return __builtin_bit_cast(unsigned, h);
}
__device__ __forceinline__ float2 unpackh2(unsigned u) {
  __half2 h = __builtin_bit_cast(__half2, u);
  return __half22float2(h);
}

// ---------- top-k body ----------
// 4-row LDS layout byte offset: c -> ((c>>2)<<3) | ((c&3)<<13), max 32760 (fits u16).
// Excitation: packed records muT[13][2048] = uint4 {u16 off[4], f16 val[4]}.
// Inhibition: flat u32 offset + f32 value.
__device__ void topk_body(const float* __restrict__ W, int row, int k, int kpad,
                          float hi, float t0, float vscale,
                          uint4* __restrict__ muT,
                          unsigned* __restrict__ out_off, float* __restrict__ out_val)
{
  const int t = threadIdx.x;
  const float* wr = W + (size_t)row * INE_;

  __shared__ float cval[CAP_];
  __shared__ int   ccol[CAP_];
  __shared__ int   scnt;
  __shared__ int   red[4];

  float thr = t0;
  int M = 0;
  for (int attempt = 0; attempt < 8; ++attempt) {
    int local = 0;
    #pragma unroll
    for (int j = 0; j < 4; ++j) {
      float4 w4 = *reinterpret_cast<const float4*>(wr + 4 * (t + 256 * j));
      local += (w4.x > thr) + (w4.y > thr) + (w4.z > thr) + (w4.w > thr);
    }
    #pragma unroll
    for (int off = 32; off > 0; off >>= 1) local += __shfl_down(local, off);
    if ((t & 63) == 0) red[t >> 6] = local;
    __syncthreads();
    M = red[0] + red[1] + red[2] + red[3];
    __syncthreads();
    if (M >= k && M <= CAP_) break;
    if (M < k) thr = hi - (hi - thr) * 4.0f;
    else       thr = hi - (hi - thr) * 0.5f;
  }

  if (t == 0) scnt = 0;
  __syncthreads();
  #pragma unroll
  for (int j = 0; j < 4; ++j) {
    int cbase = 4 * (t + 256 * j);
    float4 w4 = *reinterpret_cast<const float4*>(wr + cbase);
    float wv[4] = {w4.x, w4.y, w4.z, w4.w};
    #pragma unroll
    for (int q = 0; q < 4; ++q) {
      if (wv[q] > thr) {
        int pp = atomicAdd(&scnt, 1);
        if (pp < CAP_) { cval[pp] = wv[q]; ccol[pp] = cbase + q; }
      }
    }
  }
  __syncthreads();
  M = scnt < CAP_ ? scnt : CAP_;

  for (int i = t; i < M; i += 256) {
    float wi = cval[i]; int ci = ccol[i];
    int rank = 0;
    for (int m = 0; m < M; ++m) {
      float wm = cval[m]; int cm = ccol[m];
      rank += (wm > wi || (wm == wi && cm < ci)) ? 1 : 0;
    }
    if (rank < k) {
      unsigned c = (unsigned)ci;
      unsigned off = ((c >> 2) << 3) | ((c & 3u) << 13);
      if (kpad == 1) {
        out_off[row] = off;
        out_val[row] = wi * vscale;
      } else {
        char* rec = (char*)muT + ((size_t)(rank >> 2) * D_ + row) * 16;
        reinterpret_cast<unsigned short*>(rec)[rank & 3] = (unsigned short)off;
        reinterpret_cast<__half*>(rec)[4 + (rank & 3)] =
            __float2half_rn(wi * vscale);
      }
    }
  }
  if (kpad > 1 && t < kpad - k) {
    int slot = k + t;
    char* rec = (char*)muT + ((size_t)(slot >> 2) * D_ + row) * 16;
    reinterpret_cast<unsigned short*>(rec)[slot & 3] = 0;
    reinterpret_cast<__half*>(rec)[4 + (slot & 3)] = __float2half_rn(0.0f);
  }
}

// ---------- K1: combined prep ----------
__global__ __launch_bounds__(256) void prep_kernel(
    const float* __restrict__ wexc, const float* __restrict__ winh,
    const float* __restrict__ wblk,
    uint4* __restrict__ muT,
    unsigned* __restrict__ so_inh, float* __restrict__ vi_inh,
    float* __restrict__ wdiag)
{
  const int bid = blockIdx.x;
  const float hi = 0.015625f;
  if (bid < 2048) {
    topk_body(wexc, bid, KE_, KPAD_, hi, hi * (1.0f - 200.0f / 4096.0f), 1.0f,
              muT, nullptr, nullptr);
  } else if (bid < 4096) {
    topk_body(winh, bid - 2048, 1, 1, hi, hi * (1.0f - 48.0f / 4096.0f), -50.0f,
              nullptr, so_inh, vi_inh);
  } else {
    const int t = threadIdx.x;
    #pragma unroll
    for (int j = 0; j < 8; ++j) {
      int d = t + 256 * j;
      float4 w = *reinterpret_cast<const float4*>(wblk + (size_t)d * (INBR_ + 4));
      reinterpret_cast<float4*>(wdiag)[d] = w;
    }
  }
}

// ---------- fused E+I+BR (4 rows/block, 32 KiB LDS, 4 blocks/CU) ----------
// LDS: column c at words {2*s(c), 2*s(c)+1}, s(c)=(c>>2)|((c&3)<<10);
// word 2*s(c)+p = half2(row 2p, 2p+1).
__device__ __forceinline__ uint2 ld8(const char* ldsb, unsigned off) {
  return *reinterpret_cast<const uint2*>(ldsb + off);
}

#define FMA4(R, G, WV) do {                                                \
    float2 f0 = unpackh2((G).x), f1 = unpackh2((G).y);                     \
    acc[R][0] = fmaf(f0.x, (WV), acc[R][0]);                               \
    acc[R][1] = fmaf(f0.y, (WV), acc[R][1]);                               \
    acc[R][2] = fmaf(f1.x, (WV), acc[R][2]);                               \
    acc[R][3] = fmaf(f1.y, (WV), acc[R][3]);                               \
  } while (0)

__device__ __forceinline__ void do_br(float (&acc)[4][4], int t, int b0,
                                      const float* __restrict__ xbr,
                                      const float* __restrict__ wdiag) {
  #pragma unroll
  for (int r = 0; r < 4; ++r) {
    const int d = t + 512 * r;
    float4 wb4 = reinterpret_cast<const float4*>(wdiag)[d];
    #pragma unroll
    for (int b = 0; b < 4; ++b) {
      float4 xb4 = *reinterpret_cast<const float4*>(
          xbr + (size_t)(b0 + b) * INBR_ + 4 * d);
      acc[r][b] += xb4.x * wb4.x + xb4.y * wb4.y + xb4.z * wb4.z + xb4.w * wb4.w;
    }
  }
}

__global__ __launch_bounds__(512, 8) void fused_ei(
    const float* __restrict__ xe, const float* __restrict__ xi,
    const float* __restrict__ xbr, const float* __restrict__ wdiag,
    const uint4* __restrict__ muT,
    const unsigned* __restrict__ so_inh, const float* __restrict__ vi_inh,
    float* __restrict__ act)
{
  __shared__ unsigned xs[8192];           // 32 KiB -> 4 blocks/CU
  const int t  = threadIdx.x;
  const int b0 = blockIdx.x * 4;
  const int p  = t & 1;
  const int Q  = t >> 1;

  float acc[4][4];
  #pragma unroll
  for (int r = 0; r < 4; ++r)
    #pragma unroll
    for (int b = 0; b < 4; ++b) acc[r][b] = 0.0f;

  const char* ldsb = reinterpret_cast<const char*>(xs);
  const bool brf = (blockIdx.x & 1);

  // odd blocks stream xbr FIRST: decorrelates HBM bursts across resident blocks
  if (brf) do_br(acc, t, b0, xbr, wdiag);

  // ---- stage xe into LDS ----
  {
    const float* r0p = xe + (size_t)(b0 + 2 * p)     * INE_;
    const float* r1p = xe + (size_t)(b0 + 2 * p + 1) * INE_;
    #pragma unroll
    for (int m = 0; m < 4; ++m) {
      int c0 = 4 * Q + 1024 * m;
      float4 fa = *reinterpret_cast<const float4*>(r0p + c0);
      float4 fb = *reinterpret_cast<const float4*>(r1p + c0);
      int wb = 2 * (Q + 256 * m) + p;
      xs[wb]        = packh2(fa.x, fb.x);
      xs[wb + 2048] = packh2(fa.y, fb.y);
      xs[wb + 4096] = packh2(fa.z, fb.z);
      xs[wb + 6144] = packh2(fa.w, fb.w);
    }
  }

  // ---- prefetch half of xi (row b0+2p) + inhibition metadata ----
  float4 xia[4];
  {
    const float* xr0 = xi + (size_t)(b0 + 2 * p) * INE_;
    #pragma unroll
    for (int m = 0; m < 4; ++m)
      xia[m] = *reinterpret_cast<const float4*>(xr0 + 4 * Q + 1024 * m);
  }
  unsigned oi[4]; float viv[4];
  #pragma unroll
  for (int r = 0; r < 4; ++r) {
    oi[r]  = so_inh[t + 512 * r];
    viv[r] = vi_inh[t + 512 * r];
  }
  __syncthreads();

  // ---- phase E: 13 iterations, packed metadata, r-pair batched gathers ----
  for (int ii = 0; ii < KPAD_ / 4; ++ii) {
    uint4 m[4];
    #pragma unroll
    for (int r = 0; r < 4; ++r) m[r] = muT[ii * D_ + t + 512 * r];
    #pragma unroll
    for (int half = 0; half < 2; ++half) {
      uint2 g[2][4];
      #pragma unroll
      for (int rr = 0; rr < 2; ++rr) {
        const int r = 2 * half + rr;
        g[rr][0] = ld8(ldsb, m[r].x & 0xFFFFu);
        g[rr][1] = ld8(ldsb, m[r].x >> 16);
        g[rr][2] = ld8(ldsb, m[r].y & 0xFFFFu);
        g[rr][3] = ld8(ldsb, m[r].y >> 16);
      }
      #pragma unroll
      for (int rr = 0; rr < 2; ++rr) {
        const int r = 2 * half + rr;
        float2 vA = unpackh2(m[r].z);
        float2 vB = unpackh2(m[r].w);
        FMA4(r, g[rr][0], vA.x);
        FMA4(r, g[rr][1], vA.y);
        FMA4(r, g[rr][2], vB.x);
        FMA4(r, g[rr][3], vB.y);
      }
    }
  }
  __syncthreads();

  // ---- stage xi: prefetched row from regs, other row from HBM ----
  {
    const float* xr1 = xi + (size_t)(b0 + 2 * p + 1) * INE_;
    #pragma unroll
    for (int m = 0; m < 4; ++m) {
      int c0 = 4 * Q + 1024 * m;
      float4 fb = *reinterpret_cast<const float4*>(xr1 + c0);
      int wb = 2 * (Q + 256 * m) + p;
      xs[wb]        = packh2(xia[m].x, fb.x);
      xs[wb + 2048] = packh2(xia[m].y, fb.y);
      xs[wb + 4096] = packh2(xia[m].z, fb.z);
      xs[wb + 6144] = packh2(xia[m].w, fb.w);
    }
  }
  __syncthreads();

  // ---- phase I ----
  {
    uint2 gi[4];
    #pragma unroll
    for (int r = 0; r < 4; ++r) gi[r] = ld8(ldsb, oi[r]);
    #pragma unroll
    for (int r = 0; r < 4; ++r) FMA4(r, gi[r], viv[r]);
  }

  // even blocks stream xbr LAST
  if (!brf) do_br(acc, t, b0, xbr, wdiag);

  // ---- write act ----
  #pragma unroll
  for (int r = 0; r < 4; ++r) {
    const int d = t + 512 * r;
    #pragma unroll
    for (int b = 0; b < 4; ++b)
      act[(size_t)(b0 + b) * D_ + d] = acc[r][b];
  }
}

// ---------- K3a: column sums/sumsq ----------
__global__ __launch_bounds__(256) void reduce_stats(
    const float* __restrict__ act, float* __restrict__ sums,
    float* __restrict__ sumsq)
{
  const int dg = blockIdx.x & 63;
  const int rg = blockIdx.x >> 6;
  const int tx = threadIdx.x & 31;
  const int ty = threadIdx.x >> 5;
  const int d  = dg * 32 + tx;

  float s = 0.0f, s2 = 0.0f;
  #pragma unroll 4
  for (int i = 0; i < 64; ++i) {
    int row = rg * 512 + ty + 8 * i;
    float a = act[(size_t)row * D_ + d];
    s += a;
    s2 = fmaf(a, a, s2);
  }
  __shared__ float ls[2][8][32];
  ls[0][ty][tx] = s;
  ls[1][ty][tx] = s2;
  __syncthreads();
  if (ty == 0) {
    #pragma unroll
    for (int j = 1; j < 8; ++j) { s += ls[0][j][tx]; s2 += ls[1][j][tx]; }
    atomicAdd(&sums[d], s);
    atomicAdd(&sumsq[d], s2);
  }
}

// ---------- K3b: finalize + normalize + sigmoid ----------
__global__ __launch_bounds__(256) void tail_kernel(
    const float* __restrict__ act, float* __restrict__ out,
    const float* __restrict__ sums, const float* __restrict__ sumsq,
    const float* __restrict__ gamma, const float* __restrict__ beta)
{
  __shared__ float scsh[2 * D_];
  const int tid = threadIdx.x;
  #pragma unroll
  for (int j = 0; j < 8; ++j) {
    int d = tid + 256 * j;
    float mean = sums[d]  * (1.0f / B_);
    float var  = sumsq[d] * (1.0f / B_) - mean * mean;
    float rstd = rsqrtf(var + 1e-5f);
    float sc   = gamma[d] * rstd;
    scsh[2 * d]     = sc;
    scsh[2 * d + 1] = fmaf(-mean, sc, beta[d]);
  }
  __syncthreads();

  const int r0 = blockIdx.x * 8;
  for (int rr = 0; rr < 8; ++rr) {
    const float4* ap = reinterpret_cast<const float4*>(act + (size_t)(r0 + rr) * D_);
    float4*       op = reinterpret_cast<float4*>(out + (size_t)(r0 + rr) * D_);
    #pragma unroll
    for (int i2 = 0; i2 < 2; ++i2) {
      int i = tid + 256 * i2;
      float4 a = ap[i];
      const float4* sp = reinterpret_cast<const float4*>(scsh + 8 * i);
      float4 s0 = sp[0];
      float4 s1 = sp[1];
      float z0 = fmaf(a.x, s0.x, s0.y);
      float z1 = fmaf(a.y, s0.z, s0.w);
      float z2 = fmaf(a.z, s1.x, s1.y);
      float z3 = fmaf(a.w, s1.z, s1.w);
      float4 o;
      o.x = 1.0f / (1.0f + __expf(-z0));
      o.y = 1.0f / (1.0f + __expf(-z1));
      o.z = 1.0f / (1.0f + __expf(-z2));
      o.w = 1.0f / (1.0f + __expf(-z3));
      op[i] = o;
    }
  }
}

extern "C" void kernel_launch(void* const* d_in, const int* in_sizes, int n_in,
                              void* d_out, int out_size, void* d_ws, size_t ws_size,
                              hipStream_t stream) {
  const float* xe    = (const float*)d_in[0];
  const float* xi    = (const float*)d_in[1];
  const float* xbr   = (const float*)d_in[2];
  const float* wexc  = (const float*)d_in[3];
  const float* winh  = (const float*)d_in[4];
  const float* wblk  = (const float*)d_in[5];
  const float* gamma = (const float*)d_in[6];
  const float* beta  = (const float*)d_in[7];
  float* out = (float*)d_out;

  char* ws = (char*)d_ws;
  uint4*    muT    = (uint4*)   (ws + 0);         // [13][2048] uint4
  unsigned* so_inh = (unsigned*)(ws + 425984);
  float*    vi_inh = (float*)   (ws + 434176);
  float*    wdiag  = (float*)   (ws + 442368);
  float*    sums   = (float*)   (ws + 475136);
  float*    sumsq  = (float*)   (ws + 483328);
  float*    act    = (float*)   (ws + 1048576);   // 32 MiB

  hipMemsetAsync(sums, 0, 2 * D_ * sizeof(float), stream);

  prep_kernel<<<dim3(4097), dim3(256), 0, stream>>>(
      wexc, winh, wblk, muT, so_inh, vi_inh, wdiag);
  fused_ei<<<dim3(B_ / 4), dim3(512), 0, stream>>>(
      xe, xi, xbr, wdiag, muT, so_inh, vi_inh, act);
  reduce_stats<<<dim3(512), dim3(256), 0, stream>>>(act, sums, sumsq);
  tail_kernel<<<dim3(512), dim3(256), 0, stream>>>(
      act, out, sums, sumsq, gamma, beta);
}

// Round 12
// 125.785 us; speedup vs baseline: 2.6231x; 1.1510x over previous
//
#include <hip/hip_runtime.h>
#include <hip/hip_fp16.h>

#define B_     4096
#define INE_   4096
#define INBR_  8192
#define D_     2048
#define KE_    50
#define KPAD_  52
#define CAP_   512
#define NSL_   4

// ---------- helpers ----------
__device__ __forceinline__ unsigned packh2(float a, float b) {
  __half2 h = __floats2half2_rn(a, b);
  return __builtin_bit_cast(unsigned, h);
}
__device__ __forceinline__ float2 unpackh2(unsigned u) {
  __half2 h = __builtin_bit_cast(__half2, u);
  return __half22float2(h);
}

// ---------- top-k body ----------
// 4-row LDS byte offset: c -> ((c>>2)<<3) | ((c&3)<<13), max 32760 (fits u16).
// Excitation: packed muT[13][2048] = uint4 {u16 off[4], f16 val[4]}.
__device__ void topk_body(const float* __restrict__ W, int row, int k, int kpad,
                          float hi, float t0, float vscale,
                          uint4* __restrict__ muT,
                          unsigned* __restrict__ out_off, float* __restrict__ out_val)
{
  const int t = threadIdx.x;
  const float* wr = W + (size_t)row * INE_;

  __shared__ float cval[CAP_];
  __shared__ int   ccol[CAP_];
  __shared__ int   scnt;
  __shared__ int   red[4];

  float thr = t0;
  int M = 0;
  for (int attempt = 0; attempt < 8; ++attempt) {
    int local = 0;
    #pragma unroll
    for (int j = 0; j < 4; ++j) {
      float4 w4 = *reinterpret_cast<const float4*>(wr + 4 * (t + 256 * j));
      local += (w4.x > thr) + (w4.y > thr) + (w4.z > thr) + (w4.w > thr);
    }
    #pragma unroll
    for (int off = 32; off > 0; off >>= 1) local += __shfl_down(local, off);
    if ((t & 63) == 0) red[t >> 6] = local;
    __syncthreads();
    M = red[0] + red[1] + red[2] + red[3];
    __syncthreads();
    if (M >= k && M <= CAP_) break;
    if (M < k) thr = hi - (hi - thr) * 4.0f;
    else       thr = hi - (hi - thr) * 0.5f;
  }

  if (t == 0) scnt = 0;
  __syncthreads();
  #pragma unroll
  for (int j = 0; j < 4; ++j) {
    int cbase = 4 * (t + 256 * j);
    float4 w4 = *reinterpret_cast<const float4*>(wr + cbase);
    float wv[4] = {w4.x, w4.y, w4.z, w4.w};
    #pragma unroll
    for (int q = 0; q < 4; ++q) {
      if (wv[q] > thr) {
        int pp = atomicAdd(&scnt, 1);
        if (pp < CAP_) { cval[pp] = wv[q]; ccol[pp] = cbase + q; }
      }
    }
  }
  __syncthreads();
  M = scnt < CAP_ ? scnt : CAP_;

  for (int i = t; i < M; i += 256) {
    float wi = cval[i]; int ci = ccol[i];
    int rank = 0;
    for (int m = 0; m < M; ++m) {
      float wm = cval[m]; int cm = ccol[m];
      rank += (wm > wi || (wm == wi && cm < ci)) ? 1 : 0;
    }
    if (rank < k) {
      unsigned c = (unsigned)ci;
      unsigned off = ((c >> 2) << 3) | ((c & 3u) << 13);
      if (kpad == 1) {
        out_off[row] = off;
        out_val[row] = wi * vscale;
      } else {
        char* rec = (char*)muT + ((size_t)(rank >> 2) * D_ + row) * 16;
        reinterpret_cast<unsigned short*>(rec)[rank & 3] = (unsigned short)off;
        reinterpret_cast<__half*>(rec)[4 + (rank & 3)] =
            __float2half_rn(wi * vscale);
      }
    }
  }
  if (kpad > 1 && t < kpad - k) {
    int slot = k + t;
    char* rec = (char*)muT + ((size_t)(slot >> 2) * D_ + row) * 16;
    reinterpret_cast<unsigned short*>(rec)[slot & 3] = 0;
    reinterpret_cast<__half*>(rec)[4 + (slot & 3)] = __float2half_rn(0.0f);
  }
}

// ---------- K1: combined prep ----------
__global__ __launch_bounds__(256) void prep_kernel(
    const float* __restrict__ wexc, const float* __restrict__ winh,
    const float* __restrict__ wblk,
    uint4* __restrict__ muT,
    unsigned* __restrict__ so_inh, float* __restrict__ vi_inh,
    float* __restrict__ wdiag)
{
  const int bid = blockIdx.x;
  const float hi = 0.015625f;
  if (bid < 2048) {
    topk_body(wexc, bid, KE_, KPAD_, hi, hi * (1.0f - 200.0f / 4096.0f), 1.0f,
              muT, nullptr, nullptr);
  } else if (bid < 4096) {
    topk_body(winh, bid - 2048, 1, 1, hi, hi * (1.0f - 48.0f / 4096.0f), -50.0f,
              nullptr, so_inh, vi_inh);
  } else {
    const int t = threadIdx.x;
    #pragma unroll
    for (int j = 0; j < 8; ++j) {
      int d = t + 256 * j;
      float4 w = *reinterpret_cast<const float4*>(wblk + (size_t)d * (INBR_ + 4));
      reinterpret_cast<float4*>(wdiag)[d] = w;
    }
  }
}

// ---------- fused E+I+BR+stats (4 rows/block, 32 KiB LDS) ----------
__device__ __forceinline__ uint2 ld8(const char* ldsb, unsigned off) {
  return *reinterpret_cast<const uint2*>(ldsb + off);
}

#define FMA4(R, G, WV) do {                                                \
    float2 f0 = unpackh2((G).x), f1 = unpackh2((G).y);                     \
    acc[R][0] = fmaf(f0.x, (WV), acc[R][0]);                               \
    acc[R][1] = fmaf(f0.y, (WV), acc[R][1]);                               \
    acc[R][2] = fmaf(f1.x, (WV), acc[R][2]);                               \
    acc[R][3] = fmaf(f1.y, (WV), acc[R][3]);                               \
  } while (0)

__device__ __forceinline__ void do_br(float (&acc)[4][4], int t, int b0,
                                      const float* __restrict__ xbr,
                                      const float* __restrict__ wdiag) {
  #pragma unroll
  for (int r = 0; r < 4; ++r) {
    const int d = t + 512 * r;
    float4 wb4 = reinterpret_cast<const float4*>(wdiag)[d];
    #pragma unroll
    for (int b = 0; b < 4; ++b) {
      float4 xb4 = *reinterpret_cast<const float4*>(
          xbr + (size_t)(b0 + b) * INBR_ + 4 * d);
      acc[r][b] += xb4.x * wb4.x + xb4.y * wb4.y + xb4.z * wb4.z + xb4.w * wb4.w;
    }
  }
}

__global__ __launch_bounds__(512, 4) void fused_ei(
    const float* __restrict__ xe, const float* __restrict__ xi,
    const float* __restrict__ xbr, const float* __restrict__ wdiag,
    const uint4* __restrict__ muT,
    const unsigned* __restrict__ so_inh, const float* __restrict__ vi_inh,
    float* __restrict__ act, float* __restrict__ sums_p,
    float* __restrict__ sumsq_p)
{
  __shared__ unsigned xs[8192];           // 32 KiB
  const int t  = threadIdx.x;
  const int b0 = blockIdx.x * 4;
  const int p  = t & 1;
  const int Q  = t >> 1;

  float acc[4][4];
  #pragma unroll
  for (int r = 0; r < 4; ++r)
    #pragma unroll
    for (int b = 0; b < 4; ++b) acc[r][b] = 0.0f;

  const char* ldsb = reinterpret_cast<const char*>(xs);
  const bool brf = (blockIdx.x & 1);

  // odd blocks stream xbr FIRST: decorrelate HBM bursts across resident blocks
  if (brf) do_br(acc, t, b0, xbr, wdiag);

  // ---- stage xe ----
  {
    const float* r0p = xe + (size_t)(b0 + 2 * p)     * INE_;
    const float* r1p = xe + (size_t)(b0 + 2 * p + 1) * INE_;
    #pragma unroll
    for (int m = 0; m < 4; ++m) {
      int c0 = 4 * Q + 1024 * m;
      float4 fa = *reinterpret_cast<const float4*>(r0p + c0);
      float4 fb = *reinterpret_cast<const float4*>(r1p + c0);
      int wb = 2 * (Q + 256 * m) + p;
      xs[wb]        = packh2(fa.x, fb.x);
      xs[wb + 2048] = packh2(fa.y, fb.y);
      xs[wb + 4096] = packh2(fa.z, fb.z);
      xs[wb + 6144] = packh2(fa.w, fb.w);
    }
  }

  // ---- prefetch xi (row b0+2p) + inhibition metadata ----
  float4 xia[4];
  {
    const float* xr0 = xi + (size_t)(b0 + 2 * p) * INE_;
    #pragma unroll
    for (int m = 0; m < 4; ++m)
      xia[m] = *reinterpret_cast<const float4*>(xr0 + 4 * Q + 1024 * m);
  }
  unsigned oi[4]; float viv[4];
  #pragma unroll
  for (int r = 0; r < 4; ++r) {
    oi[r]  = so_inh[t + 512 * r];
    viv[r] = vi_inh[t + 512 * r];
  }
  __syncthreads();

  // ---- phase E ----
  for (int ii = 0; ii < KPAD_ / 4; ++ii) {
    uint4 m[4];
    #pragma unroll
    for (int r = 0; r < 4; ++r) m[r] = muT[ii * D_ + t + 512 * r];
    #pragma unroll
    for (int half = 0; half < 2; ++half) {
      uint2 g[2][4];
      #pragma unroll
      for (int rr = 0; rr < 2; ++rr) {
        const int r = 2 * half + rr;
        g[rr][0] = ld8(ldsb, m[r].x & 0xFFFFu);
        g[rr][1] = ld8(ldsb, m[r].x >> 16);
        g[rr][2] = ld8(ldsb, m[r].y & 0xFFFFu);
        g[rr][3] = ld8(ldsb, m[r].y >> 16);
      }
      #pragma unroll
      for (int rr = 0; rr < 2; ++rr) {
        const int r = 2 * half + rr;
        float2 vA = unpackh2(m[r].z);
        float2 vB = unpackh2(m[r].w);
        FMA4(r, g[rr][0], vA.x);
        FMA4(r, g[rr][1], vA.y);
        FMA4(r, g[rr][2], vB.x);
        FMA4(r, g[rr][3], vB.y);
      }
    }
  }
  __syncthreads();

  // ---- stage xi (half from regs, half from HBM) ----
  {
    const float* xr1 = xi + (size_t)(b0 + 2 * p + 1) * INE_;
    #pragma unroll
    for (int m = 0; m < 4; ++m) {
      int c0 = 4 * Q + 1024 * m;
      float4 fb = *reinterpret_cast<const float4*>(xr1 + c0);
      int wb = 2 * (Q + 256 * m) + p;
      xs[wb]        = packh2(xia[m].x, fb.x);
      xs[wb + 2048] = packh2(xia[m].y, fb.y);
      xs[wb + 4096] = packh2(xia[m].z, fb.z);
      xs[wb + 6144] = packh2(xia[m].w, fb.w);
    }
  }
  __syncthreads();

  // ---- phase I ----
  {
    uint2 gi[4];
    #pragma unroll
    for (int r = 0; r < 4; ++r) gi[r] = ld8(ldsb, oi[r]);
    #pragma unroll
    for (int r = 0; r < 4; ++r) FMA4(r, gi[r], viv[r]);
  }

  // even blocks stream xbr LAST
  if (!brf) do_br(acc, t, b0, xbr, wdiag);

  // ---- write act + sliced BN partials (each d owned by this thread) ----
  const int slice = blockIdx.x & (NSL_ - 1);
  #pragma unroll
  for (int r = 0; r < 4; ++r) {
    const int d = t + 512 * r;
    float s = 0.0f, s2 = 0.0f;
    #pragma unroll
    for (int b = 0; b < 4; ++b) {
      float a = acc[r][b];
      act[(size_t)(b0 + b) * D_ + d] = a;
      s += a;
      s2 = fmaf(a, a, s2);
    }
    atomicAdd(&sums_p[slice * D_ + d], s);
    atomicAdd(&sumsq_p[slice * D_ + d], s2);
  }
}

// ---------- tail: finalize stats + normalize + sigmoid -> d_out ----------
__global__ __launch_bounds__(256) void tail_kernel(
    const float* __restrict__ act, float* __restrict__ out,
    const float* __restrict__ sums_p, const float* __restrict__ sumsq_p,
    const float* __restrict__ gamma, const float* __restrict__ beta)
{
  __shared__ float scsh[2 * D_];
  const int tid = threadIdx.x;
  #pragma unroll
  for (int j = 0; j < 8; ++j) {
    int d = tid + 256 * j;
    float s = 0.0f, s2 = 0.0f;
    #pragma unroll
    for (int sl = 0; sl < NSL_; ++sl) {
      s  += sums_p[sl * D_ + d];
      s2 += sumsq_p[sl * D_ + d];
    }
    float mean = s  * (1.0f / B_);
    float var  = s2 * (1.0f / B_) - mean * mean;
    float rstd = rsqrtf(var + 1e-5f);
    float sc   = gamma[d] * rstd;
    scsh[2 * d]     = sc;
    scsh[2 * d + 1] = fmaf(-mean, sc, beta[d]);
  }
  __syncthreads();

  const int r0 = blockIdx.x * 8;
  for (int rr = 0; rr < 8; ++rr) {
    const float4* ap = reinterpret_cast<const float4*>(act + (size_t)(r0 + rr) * D_);
    float4*       op = reinterpret_cast<float4*>(out + (size_t)(r0 + rr) * D_);
    #pragma unroll
    for (int i2 = 0; i2 < 2; ++i2) {
      int i = tid + 256 * i2;
      float4 a = ap[i];
      const float4* sp = reinterpret_cast<const float4*>(scsh + 8 * i);
      float4 s0 = sp[0];
      float4 s1 = sp[1];
      float z0 = fmaf(a.x, s0.x, s0.y);
      float z1 = fmaf(a.y, s0.z, s0.w);
      float z2 = fmaf(a.z, s1.x, s1.y);
      float z3 = fmaf(a.w, s1.z, s1.w);
      float4 o;
      o.x = 1.0f / (1.0f + __expf(-z0));
      o.y = 1.0f / (1.0f + __expf(-z1));
      o.z = 1.0f / (1.0f + __expf(-z2));
      o.w = 1.0f / (1.0f + __expf(-z3));
      op[i] = o;
    }
  }
}

extern "C" void kernel_launch(void* const* d_in, const int* in_sizes, int n_in,
                              void* d_out, int out_size, void* d_ws, size_t ws_size,
                              hipStream_t stream) {
  const float* xe    = (const float*)d_in[0];
  const float* xi    = (const float*)d_in[1];
  const float* xbr   = (const float*)d_in[2];
  const float* wexc  = (const float*)d_in[3];
  const float* winh  = (const float*)d_in[4];
  const float* wblk  = (const float*)d_in[5];
  const float* gamma = (const float*)d_in[6];
  const float* beta  = (const float*)d_in[7];
  float* out = (float*)d_out;

  char* ws = (char*)d_ws;
  uint4*    muT     = (uint4*)   (ws + 0);         // [13][2048] uint4
  unsigned* so_inh  = (unsigned*)(ws + 425984);
  float*    vi_inh  = (float*)   (ws + 434176);
  float*    wdiag   = (float*)   (ws + 442368);    // ends 475136
  float*    sums_p  = (float*)   (ws + 475136);    // [4][2048] f32
  float*    sumsq_p = (float*)   (ws + 507904);    // [4][2048] f32 (ends 540672)
  float*    act     = (float*)   (ws + 1048576);   // 32 MiB

  hipMemsetAsync(sums_p, 0, 2 * NSL_ * D_ * sizeof(float), stream);

  prep_kernel<<<dim3(4097), dim3(256), 0, stream>>>(
      wexc, winh, wblk, muT, so_inh, vi_inh, wdiag);
  fused_ei<<<dim3(B_ / 4), dim3(512), 0, stream>>>(
      xe, xi, xbr, wdiag, muT, so_inh, vi_inh, act, sums_p, sumsq_p);
  tail_kernel<<<dim3(512), dim3(256), 0, stream>>>(
      act, out, sums_p, sumsq_p, gamma, beta);
}

// Round 13
// 124.604 us; speedup vs baseline: 2.6480x; 1.0095x over previous
//
#include <hip/hip_runtime.h>
#include <hip/hip_fp16.h>

#define B_     4096
#define INE_   4096
#define INBR_  8192
#define D_     2048
#define KE_    50
#define KPAD_  52
#define CAP_   512
#define NSL_   4

// ---------- helpers ----------
__device__ __forceinline__ unsigned packh2(float a, float b) {
  __half2 h = __floats2half2_rn(a, b);
  return __builtin_bit_cast(unsigned, h);
}
__device__ __forceinline__ float2 unpackh2(unsigned u) {
  __half2 h = __builtin_bit_cast(__half2, u);
  return __half22float2(h);
}

// ---------- top-k body ----------
// Excitation (kpad>1): packed muT[13][2048] = uint4 {u16 off[4], f16 val[4]},
//   off = 4-row LDS byte offset: ((c>>2)<<3) | ((c&3)<<13)  (max 32760).
// Inhibition (kpad==1): out_off[row] = RAW COLUMN index, out_val = -50*w.
__device__ void topk_body(const float* __restrict__ W, int row, int k, int kpad,
                          float hi, float t0, float vscale,
                          uint4* __restrict__ muT,
                          unsigned* __restrict__ out_off, float* __restrict__ out_val)
{
  const int t = threadIdx.x;
  const float* wr = W + (size_t)row * INE_;

  __shared__ float cval[CAP_];
  __shared__ int   ccol[CAP_];
  __shared__ int   scnt;
  __shared__ int   red[4];

  float thr = t0;
  int M = 0;
  for (int attempt = 0; attempt < 8; ++attempt) {
    int local = 0;
    #pragma unroll
    for (int j = 0; j < 4; ++j) {
      float4 w4 = *reinterpret_cast<const float4*>(wr + 4 * (t + 256 * j));
      local += (w4.x > thr) + (w4.y > thr) + (w4.z > thr) + (w4.w > thr);
    }
    #pragma unroll
    for (int off = 32; off > 0; off >>= 1) local += __shfl_down(local, off);
    if ((t & 63) == 0) red[t >> 6] = local;
    __syncthreads();
    M = red[0] + red[1] + red[2] + red[3];
    __syncthreads();
    if (M >= k && M <= CAP_) break;
    if (M < k) thr = hi - (hi - thr) * 4.0f;
    else       thr = hi - (hi - thr) * 0.5f;
  }

  if (t == 0) scnt = 0;
  __syncthreads();
  #pragma unroll
  for (int j = 0; j < 4; ++j) {
    int cbase = 4 * (t + 256 * j);
    float4 w4 = *reinterpret_cast<const float4*>(wr + cbase);
    float wv[4] = {w4.x, w4.y, w4.z, w4.w};
    #pragma unroll
    for (int q = 0; q < 4; ++q) {
      if (wv[q] > thr) {
        int pp = atomicAdd(&scnt, 1);
        if (pp < CAP_) { cval[pp] = wv[q]; ccol[pp] = cbase + q; }
      }
    }
  }
  __syncthreads();
  M = scnt < CAP_ ? scnt : CAP_;

  for (int i = t; i < M; i += 256) {
    float wi = cval[i]; int ci = ccol[i];
    int rank = 0;
    for (int m = 0; m < M; ++m) {
      float wm = cval[m]; int cm = ccol[m];
      rank += (wm > wi || (wm == wi && cm < ci)) ? 1 : 0;
    }
    if (rank < k) {
      unsigned c = (unsigned)ci;
      if (kpad == 1) {
        out_off[row] = c;                       // raw column for direct gather
        out_val[row] = wi * vscale;
      } else {
        unsigned off = ((c >> 2) << 3) | ((c & 3u) << 13);
        char* rec = (char*)muT + ((size_t)(rank >> 2) * D_ + row) * 16;
        reinterpret_cast<unsigned short*>(rec)[rank & 3] = (unsigned short)off;
        reinterpret_cast<__half*>(rec)[4 + (rank & 3)] =
            __float2half_rn(wi * vscale);
      }
    }
  }
  if (kpad > 1 && t < kpad - k) {
    int slot = k + t;
    char* rec = (char*)muT + ((size_t)(slot >> 2) * D_ + row) * 16;
    reinterpret_cast<unsigned short*>(rec)[slot & 3] = 0;
    reinterpret_cast<__half*>(rec)[4 + (slot & 3)] = __float2half_rn(0.0f);
  }
}

// ---------- K1: combined prep ----------
__global__ __launch_bounds__(256) void prep_kernel(
    const float* __restrict__ wexc, const float* __restrict__ winh,
    const float* __restrict__ wblk,
    uint4* __restrict__ muT,
    unsigned* __restrict__ so_inh, float* __restrict__ vi_inh,
    float* __restrict__ wdiag)
{
  const int bid = blockIdx.x;
  const float hi = 0.015625f;
  if (bid < 2048) {
    topk_body(wexc, bid, KE_, KPAD_, hi, hi * (1.0f - 200.0f / 4096.0f), 1.0f,
              muT, nullptr, nullptr);
  } else if (bid < 4096) {
    topk_body(winh, bid - 2048, 1, 1, hi, hi * (1.0f - 48.0f / 4096.0f), -50.0f,
              nullptr, so_inh, vi_inh);
  } else {
    const int t = threadIdx.x;
    #pragma unroll
    for (int j = 0; j < 8; ++j) {
      int d = t + 256 * j;
      float4 w = *reinterpret_cast<const float4*>(wblk + (size_t)d * (INBR_ + 4));
      reinterpret_cast<float4*>(wdiag)[d] = w;
    }
  }
}

// ---------- fused E+I+BR+stats (4 rows/block, 32 KiB LDS, 1 barrier) ----------
__device__ __forceinline__ uint2 ld8(const char* ldsb, unsigned off) {
  return *reinterpret_cast<const uint2*>(ldsb + off);
}

#define FMA4(R, G, WV) do {                                                \
    float2 f0 = unpackh2((G).x), f1 = unpackh2((G).y);                     \
    acc[R][0] = fmaf(f0.x, (WV), acc[R][0]);                               \
    acc[R][1] = fmaf(f0.y, (WV), acc[R][1]);                               \
    acc[R][2] = fmaf(f1.x, (WV), acc[R][2]);                               \
    acc[R][3] = fmaf(f1.y, (WV), acc[R][3]);                               \
  } while (0)

__global__ __launch_bounds__(512, 4) void fused_ei(
    const float* __restrict__ xe, const float* __restrict__ xi,
    const float* __restrict__ xbr, const float* __restrict__ wdiag,
    const uint4* __restrict__ muT,
    const unsigned* __restrict__ so_inh, const float* __restrict__ vi_inh,
    __half* __restrict__ act_h, float* __restrict__ sums_p,
    float* __restrict__ sumsq_p)
{
  __shared__ unsigned xs[8192];           // 32 KiB
  const int t  = threadIdx.x;
  const int b0 = blockIdx.x * 4;
  const int p  = t & 1;
  const int Q  = t >> 1;

  float acc[4][4];
  #pragma unroll
  for (int r = 0; r < 4; ++r)
    #pragma unroll
    for (int b = 0; b < 4; ++b) acc[r][b] = 0.0f;

  const char* ldsb = reinterpret_cast<const char*>(xs);

  // ---- stage xe into LDS (the only staged input) ----
  {
    const float* r0p = xe + (size_t)(b0 + 2 * p)     * INE_;
    const float* r1p = xe + (size_t)(b0 + 2 * p + 1) * INE_;
    #pragma unroll
    for (int m = 0; m < 4; ++m) {
      int c0 = 4 * Q + 1024 * m;
      float4 fa = *reinterpret_cast<const float4*>(r0p + c0);
      float4 fb = *reinterpret_cast<const float4*>(r1p + c0);
      int wb = 2 * (Q + 256 * m) + p;
      xs[wb]        = packh2(fa.x, fb.x);
      xs[wb + 2048] = packh2(fa.y, fb.y);
      xs[wb + 4096] = packh2(fa.z, fb.z);
      xs[wb + 6144] = packh2(fa.w, fb.w);
    }
  }

  // ---- phase I setup: direct scattered xi gathers, issued EARLY so the
  //      ~300cy HBM/L2 latency hides under phase E (T14 pattern) ----
  unsigned ci[4]; float viv[4];
  #pragma unroll
  for (int r = 0; r < 4; ++r) {
    ci[r]  = so_inh[t + 512 * r];
    viv[r] = vi_inh[t + 512 * r];
  }
  float xg0[4], xg1[4], xg2[4], xg3[4];
  #pragma unroll
  for (int b = 0; b < 4; ++b) {
    const float* xrow = xi + (size_t)(b0 + b) * INE_;
    xg0[b] = xrow[ci[0]];
    xg1[b] = xrow[ci[1]];
    xg2[b] = xrow[ci[2]];
    xg3[b] = xrow[ci[3]];
  }
  __syncthreads();                         // xe staged; ONLY barrier

  // ---- phase E: 13 iterations, packed metadata ----
  for (int ii = 0; ii < KPAD_ / 4; ++ii) {
    uint4 m[4];
    #pragma unroll
    for (int r = 0; r < 4; ++r) m[r] = muT[ii * D_ + t + 512 * r];
    #pragma unroll
    for (int half = 0; half < 2; ++half) {
      uint2 g[2][4];
      #pragma unroll
      for (int rr = 0; rr < 2; ++rr) {
        const int r = 2 * half + rr;
        g[rr][0] = ld8(ldsb, m[r].x & 0xFFFFu);
        g[rr][1] = ld8(ldsb, m[r].x >> 16);
        g[rr][2] = ld8(ldsb, m[r].y & 0xFFFFu);
        g[rr][3] = ld8(ldsb, m[r].y >> 16);
      }
      #pragma unroll
      for (int rr = 0; rr < 2; ++rr) {
        const int r = 2 * half + rr;
        float2 vA = unpackh2(m[r].z);
        float2 vB = unpackh2(m[r].w);
        FMA4(r, g[rr][0], vA.x);
        FMA4(r, g[rr][1], vA.y);
        FMA4(r, g[rr][2], vB.x);
        FMA4(r, g[rr][3], vB.y);
      }
    }
  }

  // ---- phase I: consume prefetched gathers (register-only) ----
  #pragma unroll
  for (int b = 0; b < 4; ++b) {
    acc[0][b] = fmaf(xg0[b], viv[0], acc[0][b]);
    acc[1][b] = fmaf(xg1[b], viv[1], acc[1][b]);
    acc[2][b] = fmaf(xg2[b], viv[2], acc[2][b]);
    acc[3][b] = fmaf(xg3[b], viv[3], acc[3][b]);
  }

  // ---- phase BR: block-diagonal depolarization (coalesced stream) ----
  #pragma unroll
  for (int r = 0; r < 4; ++r) {
    const int d = t + 512 * r;
    float4 wb4 = reinterpret_cast<const float4*>(wdiag)[d];
    #pragma unroll
    for (int b = 0; b < 4; ++b) {
      float4 xb4 = *reinterpret_cast<const float4*>(
          xbr + (size_t)(b0 + b) * INBR_ + 4 * d);
      acc[r][b] += xb4.x * wb4.x + xb4.y * wb4.y + xb4.z * wb4.z + xb4.w * wb4.w;
    }
  }

  // ---- write act (f16) + sliced BN partials (stats from f32 acc) ----
  const int slice = blockIdx.x & (NSL_ - 1);
  #pragma unroll
  for (int r = 0; r < 4; ++r) {
    const int d = t + 512 * r;
    float s = 0.0f, s2 = 0.0f;
    #pragma unroll
    for (int b = 0; b < 4; ++b) {
      float a = acc[r][b];
      act_h[(size_t)(b0 + b) * D_ + d] = __float2half_rn(a);
      s += a;
      s2 = fmaf(a, a, s2);
    }
    atomicAdd(&sums_p[slice * D_ + d], s);
    atomicAdd(&sumsq_p[slice * D_ + d], s2);
  }
}

// ---------- tail: finalize stats + normalize + sigmoid -> d_out ----------
__global__ __launch_bounds__(256) void tail_kernel(
    const __half* __restrict__ act_h, float* __restrict__ out,
    const float* __restrict__ sums_p, const float* __restrict__ sumsq_p,
    const float* __restrict__ gamma, const float* __restrict__ beta)
{
  __shared__ float scsh[2 * D_];
  const int tid = threadIdx.x;
  #pragma unroll
  for (int j = 0; j < 8; ++j) {
    int d = tid + 256 * j;
    float s = 0.0f, s2 = 0.0f;
    #pragma unroll
    for (int sl = 0; sl < NSL_; ++sl) {
      s  += sums_p[sl * D_ + d];
      s2 += sumsq_p[sl * D_ + d];
    }
    float mean = s  * (1.0f / B_);
    float var  = s2 * (1.0f / B_) - mean * mean;
    float rstd = rsqrtf(var + 1e-5f);
    float sc   = gamma[d] * rstd;
    scsh[2 * d]     = sc;
    scsh[2 * d + 1] = fmaf(-mean, sc, beta[d]);
  }
  __syncthreads();

  const int r0 = blockIdx.x * 8;
  for (int rr = 0; rr < 8; ++rr) {
    const uint2* ap = reinterpret_cast<const uint2*>(act_h + (size_t)(r0 + rr) * D_);
    float4*      op = reinterpret_cast<float4*>(out + (size_t)(r0 + rr) * D_);
    #pragma unroll
    for (int i2 = 0; i2 < 2; ++i2) {
      int i = tid + 256 * i2;
      uint2 aw = ap[i];                    // 4 halves = act[4i..4i+3]
      float2 f0 = unpackh2(aw.x);
      float2 f1 = unpackh2(aw.y);
      const float4* sp = reinterpret_cast<const float4*>(scsh + 8 * i);
      float4 s0 = sp[0];
      float4 s1 = sp[1];
      float z0 = fmaf(f0.x, s0.x, s0.y);
      float z1 = fmaf(f0.y, s0.z, s0.w);
      float z2 = fmaf(f1.x, s1.x, s1.y);
      float z3 = fmaf(f1.y, s1.z, s1.w);
      float4 o;
      o.x = 1.0f / (1.0f + __expf(-z0));
      o.y = 1.0f / (1.0f + __expf(-z1));
      o.z = 1.0f / (1.0f + __expf(-z2));
      o.w = 1.0f / (1.0f + __expf(-z3));
      op[i] = o;
    }
  }
}

extern "C" void kernel_launch(void* const* d_in, const int* in_sizes, int n_in,
                              void* d_out, int out_size, void* d_ws, size_t ws_size,
                              hipStream_t stream) {
  const float* xe    = (const float*)d_in[0];
  const float* xi    = (const float*)d_in[1];
  const float* xbr   = (const float*)d_in[2];
  const float* wexc  = (const float*)d_in[3];
  const float* winh  = (const float*)d_in[4];
  const float* wblk  = (const float*)d_in[5];
  const float* gamma = (const float*)d_in[6];
  const float* beta  = (const float*)d_in[7];
  float* out = (float*)d_out;

  char* ws = (char*)d_ws;
  uint4*    muT     = (uint4*)   (ws + 0);         // [13][2048] uint4
  unsigned* so_inh  = (unsigned*)(ws + 425984);
  float*    vi_inh  = (float*)   (ws + 434176);
  float*    wdiag   = (float*)   (ws + 442368);    // ends 475136
  float*    sums_p  = (float*)   (ws + 475136);    // [4][2048] f32
  float*    sumsq_p = (float*)   (ws + 507904);    // [4][2048] f32 (ends 540672)
  __half*   act_h   = (__half*)  (ws + 1048576);   // [4096][2048] f16 = 16 MiB

  hipMemsetAsync(sums_p, 0, 2 * NSL_ * D_ * sizeof(float), stream);

  prep_kernel<<<dim3(4097), dim3(256), 0, stream>>>(
      wexc, winh, wblk, muT, so_inh, vi_inh, wdiag);
  fused_ei<<<dim3(B_ / 4), dim3(512), 0, stream>>>(
      xe, xi, xbr, wdiag, muT, so_inh, vi_inh, act_h, sums_p, sumsq_p);
  tail_kernel<<<dim3(512), dim3(256), 0, stream>>>(
      act_h, out, sums_p, sumsq_p, gamma, beta);
}